// Round 4
// baseline (21.198 us; speedup 1.0000x reference)
//
#include <hip/hip_runtime.h>
#include <math.h>

#define NC   16
#define NCH  8                  // channels per thread (2 threads per position)
#define HWSZ (128 * 128)
#define NB   16
#define TOT  (NB * NC * HWSZ)   // 4,194,304 elements per output tensor

// Branchless erf, Abramowitz-Stegun 7.1.26, |err| <= 1.5e-7.
__device__ __forceinline__ float fast_erf(float v) {
    const float ax = fabsf(v);
    const float t  = __fdividef(1.0f, fmaf(0.3275911f, ax, 1.0f));
    float p = fmaf(1.061405429f, t, -1.453152027f);
    p = fmaf(p, t,  1.421413741f);
    p = fmaf(p, t, -0.284496736f);
    p = fmaf(p, t,  0.254829592f);
    p *= t;
    const float e = __expf(-v * v);
    return copysignf(fmaf(-p, e, 1.0f), v);
}

__global__ __launch_bounds__(256, 8) void moe_router_kernel(
    const float* __restrict__ x, const float* __restrict__ noise,
    const float* __restrict__ gp, const float* __restrict__ wnp,
    float* __restrict__ out)
{
    const int tid = blockIdx.x * blockDim.x + threadIdx.x;
    const int sp  = tid >> 1;           // spatial position (2 threads share one)
    const int cg  = tid & 1;            // channel group: 0 -> ch 0..7, 1 -> ch 8..15
    const int b   = sp >> 14;           // / HWSZ
    const int hw  = sp & (HWSZ - 1);
    const size_t base = (size_t)b * (NC * HWSZ) + hw + (size_t)(cg * NCH) * HWSZ;

    // Per-channel state in registers (fully unrolled, compile-time indices).
    float wg[NCH], wn[NCH], hl[NCH];
    float m1 = -INFINITY, m2 = -INFINITY;
    int   amax = 0;                     // absolute channel index

    // Pass 1: loads coalesced (lane pairs share sp -> two contiguous 128B
    // segments per wave access). Compute wg, wnoise=softplus(x*wnp), Hlogits;
    // branchless local top-2 + first-occurrence argmax over this half.
    #pragma unroll
    for (int c = 0; c < NCH; ++c) {
        const float xv = __builtin_nontemporal_load(x     + base + (size_t)c * HWSZ);
        const float nv = __builtin_nontemporal_load(noise + base + (size_t)c * HWSZ);
        const int   ac = cg * NCH + c;
        const float wgv = xv * gp[ac];
        const float z   = xv * wnp[ac];
        const float spv = fmaxf(z, 0.0f) + __logf(1.0f + __expf(-fabsf(z)));
        const float h   = __builtin_fmaf(nv, spv, wgv);
        wg[c] = wgv;
        wn[c] = spv;
        hl[c] = h;
        amax = (h > m1) ? ac : amax;         // strict > : first occurrence
        m2   = fmaxf(m2, fminf(m1, h));
        m1   = fmaxf(m1, h);
    }

    // Local softmax partial sum (relative to local max m1).
    float ssum = 0.0f;
    #pragma unroll
    for (int c = 0; c < NCH; ++c)
        ssum += __expf(hl[c] - m1);

    // Cross-thread combine with the partner lane (same wave, lane ^ 1).
    const float o_m1   = __shfl_xor(m1, 1);
    const float o_m2   = __shfl_xor(m2, 1);
    const int   o_amax = __shfl_xor(amax, 1);
    const float o_sum  = __shfl_xor(ssum, 1);

    // Order as (half0, half1) so ties pick the lower channel group.
    const float m1_0 = (cg == 0) ? m1   : o_m1;
    const float m1_1 = (cg == 0) ? o_m1 : m1;
    const float m2_0 = (cg == 0) ? m2   : o_m2;
    const float m2_1 = (cg == 0) ? o_m2 : m2;
    const int   am_0 = (cg == 0) ? amax : o_amax;
    const int   am_1 = (cg == 0) ? o_amax : amax;
    const float ss_0 = (cg == 0) ? ssum : o_sum;
    const float ss_1 = (cg == 0) ? o_sum : ssum;

    const float gm1  = fmaxf(m1_0, m1_1);
    const float gm2  = fmaxf(fminf(m1_0, m1_1), fmaxf(m2_0, m2_1));
    const int   gam  = (m1_0 >= m1_1) ? am_0 : am_1;   // first-occurrence tie-break
    const float gsum = __builtin_fmaf(ss_0, __expf(m1_0 - gm1),
                                      ss_1 * __expf(m1_1 - gm1));
    const float ginv = __fdividef(1.0f, gsum);

    // Pass 3: emit G (softmax at argmax, else 0) and load_loss for my 8 chans.
    #pragma unroll
    for (int c = 0; c < NCH; ++c) {
        const int   ac  = cg * NCH + c;
        const bool  top = (ac == gam);
        const float mex = top ? gm2 : gm1;
        const float ll  = fast_erf(__fdividef(wg[c] - mex, wn[c]));
        out[base + (size_t)c * HWSZ]       = top ? ginv : 0.0f;
        out[TOT + base + (size_t)c * HWSZ] = ll;
    }
}

extern "C" void kernel_launch(void* const* d_in, const int* in_sizes, int n_in,
                              void* d_out, int out_size, void* d_ws, size_t ws_size,
                              hipStream_t stream) {
    const float* x     = (const float*)d_in[0];
    const float* noise = (const float*)d_in[1];
    const float* gp    = (const float*)d_in[2];
    const float* wnp   = (const float*)d_in[3];
    float* out = (float*)d_out;

    const int threads = NB * HWSZ * 2;    // 524288 (2 threads per position)
    const int block   = 256;
    const int grid    = threads / block;  // 2048 blocks -> 32 waves/CU
    moe_router_kernel<<<grid, block, 0, stream>>>(x, noise, gp, wnp, out);
}

// Round 5
// 18.029 us; speedup vs baseline: 1.1757x; 1.1757x over previous
//
#include <hip/hip_runtime.h>
#include <math.h>

#define NC   16
#define HWSZ (128 * 128)
#define NB   16
#define TOT  (NB * NC * HWSZ)   // 4,194,304 elements per output tensor

typedef float f4 __attribute__((ext_vector_type(4)));

// Branchless erf, Abramowitz-Stegun 7.1.26, |err| <= 1.5e-7.
__device__ __forceinline__ float fast_erf(float v) {
    const float ax = fabsf(v);
    const float t  = __fdividef(1.0f, fmaf(0.3275911f, ax, 1.0f));
    float p = fmaf(1.061405429f, t, -1.453152027f);
    p = fmaf(p, t,  1.421413741f);
    p = fmaf(p, t, -0.284496736f);
    p = fmaf(p, t,  0.254829592f);
    p *= t;
    const float e = __expf(-v * v);
    return copysignf(fmaf(-p, e, 1.0f), v);
}

__global__ __launch_bounds__(256) void moe_router_kernel(
    const float* __restrict__ x, const float* __restrict__ noise,
    const float* __restrict__ gp, const float* __restrict__ wnp,
    float* __restrict__ out)
{
    const int t  = blockIdx.x * blockDim.x + threadIdx.x;  // 65536 threads
    const int sp = t << 2;              // first of 4 consecutive positions
    const int b  = sp >> 14;            // / HWSZ
    const int hw = sp & (HWSZ - 1);
    const size_t base = (size_t)b * (NC * HWSZ) + hw;

    // Per-channel state (compile-time indexed). hl[] dropped: softmax sum is
    // folded online (one extra __expf/chan) to keep VGPRs ~176 (no spill).
    float wg[NC][4], wn[NC][4];
    float m1[4], m2[4], ssum[4];
    int   amax[4];
    #pragma unroll
    for (int j = 0; j < 4; ++j) {
        m1[j] = -INFINITY; m2[j] = -INFINITY; ssum[j] = 0.0f; amax[j] = 0;
    }

    // Pass 1: float4 loads -> 1KB contiguous per wave-instruction per stream.
    #pragma unroll
    for (int c = 0; c < NC; ++c) {
        const f4 xv = __builtin_nontemporal_load(
            reinterpret_cast<const f4*>(x     + base + (size_t)c * HWSZ));
        const f4 nv = __builtin_nontemporal_load(
            reinterpret_cast<const f4*>(noise + base + (size_t)c * HWSZ));
        const float g = gp[c];
        const float w = wnp[c];
        #pragma unroll
        for (int j = 0; j < 4; ++j) {
            const float wgv = xv[j] * g;
            const float z   = xv[j] * w;
            const float spv = fmaxf(z, 0.0f) + __logf(1.0f + __expf(-fabsf(z)));
            const float h   = __builtin_fmaf(nv[j], spv, wgv);
            wg[c][j] = wgv;
            wn[c][j] = spv;
            const float m1n = fmaxf(m1[j], h);
            // online softmax sum; __expf(-inf)=0 handles c==0 cleanly
            ssum[j] = __builtin_fmaf(ssum[j], __expf(m1[j] - m1n),
                                     __expf(h - m1n));
            amax[j] = (h > m1[j]) ? c : amax[j];   // strict > : first occurrence
            m2[j]   = fmaxf(m2[j], fminf(m1[j], h));
            m1[j]   = m1n;
        }
    }

    float ginv[4];
    #pragma unroll
    for (int j = 0; j < 4; ++j)
        ginv[j] = __fdividef(1.0f, ssum[j]);

    // Pass 2: emit G (softmax at argmax, else 0) and load_loss.
    // float4 nontemporal stores -> 1KB contiguous per wave-instruction.
    #pragma unroll
    for (int c = 0; c < NC; ++c) {
        f4 gout, lout;
        #pragma unroll
        for (int j = 0; j < 4; ++j) {
            const bool  top = (c == amax[j]);
            const float mex = top ? m2[j] : m1[j];
            lout[j] = fast_erf(__fdividef(wg[c][j] - mex, wn[c][j]));
            gout[j] = top ? ginv[j] : 0.0f;
        }
        __builtin_nontemporal_store(gout,
            reinterpret_cast<f4*>(out       + base + (size_t)c * HWSZ));
        __builtin_nontemporal_store(lout,
            reinterpret_cast<f4*>(out + TOT + base + (size_t)c * HWSZ));
    }
}

extern "C" void kernel_launch(void* const* d_in, const int* in_sizes, int n_in,
                              void* d_out, int out_size, void* d_ws, size_t ws_size,
                              hipStream_t stream) {
    const float* x     = (const float*)d_in[0];
    const float* noise = (const float*)d_in[1];
    const float* gp    = (const float*)d_in[2];
    const float* wnp   = (const float*)d_in[3];
    float* out = (float*)d_out;

    const int threads = (NB * HWSZ) / 4;  // 65536 threads, 4 positions each
    const int block   = 256;
    const int grid    = threads / block;  // 256 blocks = 1/CU
    moe_router_kernel<<<grid, block, 0, stream>>>(x, noise, gp, wnp, out);
}